// Round 1
// baseline (141.047 us; speedup 1.0000x reference)
//
#include <hip/hip_runtime.h>

// Problem: B=8, F=16, N=2048
//   w[b,i,j] = exp(-beta^2 * min(p_i,p_j) * (n_i + n_j - 2*<x_i,x_j>))
//   p_i = exp(2*alpha*log(emb[b,4,i])),  n_i = sum_f emb[b,f,i]^2
// Output 134 MB fp32 -> HBM-write-bound (~21 us floor at 6.3 TB/s).

#define BATCH 8
#define FDIM 16
#define NPT 2048
#define TILE 64

__global__ __launch_bounds__(256) void qcd_aware_kernel(
    const float* __restrict__ emb,
    const float* __restrict__ alpha_p,
    const float* __restrict__ beta_p,
    float* __restrict__ out)
{
    __shared__ float As[FDIM][TILE];
    __shared__ float Bs[FDIM][TILE];
    __shared__ float nI[TILE], nJ[TILE], pI[TILE], pJ[TILE];

    const int b  = blockIdx.z;
    const int i0 = blockIdx.y * TILE;
    const int j0 = blockIdx.x * TILE;
    const int tid = threadIdx.x;

    // ---- stage A (i-columns) and B (j-columns) tiles: 16x64 floats each ----
    {
        const int f  = tid >> 4;         // 0..15
        const int c4 = (tid & 15) * 4;   // 0,4,...,60
        const float* src = emb + ((size_t)b * FDIM + f) * NPT;
        *(float4*)&As[f][c4] = *(const float4*)(src + i0 + c4);
        *(float4*)&Bs[f][c4] = *(const float4*)(src + j0 + c4);
    }
    __syncthreads();

    const float alpha2  = 2.0f * alpha_p[0];
    const float beta    = beta_p[0];
    const float beta_sq = beta * beta;

    // ---- per-edge precompute: squared norms + pow-momenta ----
    if (tid < TILE) {
        float s = 0.f;
        #pragma unroll
        for (int f = 0; f < FDIM; ++f) { float v = As[f][tid]; s += v * v; }
        nI[tid] = s;
        pI[tid] = __expf(alpha2 * __logf(As[4][tid]));
    } else if (tid < 2 * TILE) {
        const int j = tid - TILE;
        float s = 0.f;
        #pragma unroll
        for (int f = 0; f < FDIM; ++f) { float v = Bs[f][j]; s += v * v; }
        nJ[j] = s;
        pJ[j] = __expf(alpha2 * __logf(Bs[4][j]));
    }
    __syncthreads();

    // ---- 4x4 micro-tile per thread ----
    const int jl = (tid & 15) * 4;   // 0..60
    const int il = (tid >> 4) * 4;   // 0..60

    float acc[4][4] = {};
    #pragma unroll
    for (int f = 0; f < FDIM; ++f) {
        const float4 a4 = *(const float4*)&As[f][il];
        const float4 b4 = *(const float4*)&Bs[f][jl];
        const float av[4] = {a4.x, a4.y, a4.z, a4.w};
        const float bv[4] = {b4.x, b4.y, b4.z, b4.w};
        #pragma unroll
        for (int ii = 0; ii < 4; ++ii)
            #pragma unroll
            for (int jj = 0; jj < 4; ++jj)
                acc[ii][jj] = fmaf(av[ii], bv[jj], acc[ii][jj]);
    }

    // ---- epilogue: sqdist -> weight, coalesced float4 stores ----
    float nj[4], pj[4];
    #pragma unroll
    for (int jj = 0; jj < 4; ++jj) { nj[jj] = nJ[jl + jj]; pj[jj] = pJ[jl + jj]; }

    #pragma unroll
    for (int ii = 0; ii < 4; ++ii) {
        const float ni = nI[il + ii];
        const float pi = pI[il + ii];
        float4 w;
        float* wv = (float*)&w;
        #pragma unroll
        for (int jj = 0; jj < 4; ++jj) {
            const float sqd = ni + nj[jj] - 2.0f * acc[ii][jj];
            const float mp  = fminf(pi, pj[jj]);
            wv[jj] = __expf(-beta_sq * sqd * mp);
        }
        const size_t row = (size_t)b * NPT + (size_t)(i0 + il + ii);
        *(float4*)(out + row * NPT + j0 + jl) = w;
    }
}

extern "C" void kernel_launch(void* const* d_in, const int* in_sizes, int n_in,
                              void* d_out, int out_size, void* d_ws, size_t ws_size,
                              hipStream_t stream) {
    const float* emb     = (const float*)d_in[0];
    const float* alpha_p = (const float*)d_in[1];
    const float* beta_p  = (const float*)d_in[2];
    float* out = (float*)d_out;

    dim3 grid(NPT / TILE, NPT / TILE, BATCH);  // 32 x 32 x 8
    dim3 block(256);
    qcd_aware_kernel<<<grid, block, 0, stream>>>(emb, alpha_p, beta_p, out);
}